// Round 13
// baseline (188.902 us; speedup 1.0000x reference)
//
#include <hip/hip_runtime.h>

// B=2, S=32, C=256, L=640, H=5, D=128.  M = B*S*C = 16384, L = 640 = H*D.
//
// ws layout (bytes):
//   XB   @ 0    : x bf16 [16384][640] (written only when input is fp32)
//   QB   @ SZ   : attn output [16384][640] (q/k/v never hit HBM)
//   WPK  @ 4SZ  : Wq|Wk|Wv packed FRAG-ORDER [120 nt][20 kb][64 lane][8]
//   WPPK        : Wp packed frag-order [40 nt][20 kb][64][8]
//   BPB  bp bf16 [640];  FLAG u32 (1 = inputs fp32)

typedef unsigned short u16;
typedef __bf16 bf16x8 __attribute__((ext_vector_type(8)));
typedef float f32x4 __attribute__((ext_vector_type(4)));

__device__ __forceinline__ u16 f2bf(float f){
  union { float f; unsigned u; } v; v.f = f;
  unsigned r = v.u + 0x7fffu + ((v.u >> 16) & 1u);
  return (u16)(r >> 16);
}
__device__ __forceinline__ float bf2f(u16 u){
  union { unsigned u; float f; } v; v.u = ((unsigned)u) << 16;
  return v.f;
}

__device__ __forceinline__ void gload16(const u16* g, char* l){
  __builtin_amdgcn_global_load_lds((const __attribute__((address_space(1))) void*)g,
                                   (__attribute__((address_space(3))) void*)l, 16, 0, 0);
}

// ---- LDS swizzles (verified r1-r11) ----
__device__ __forceinline__ int k_off (int e, int d){ return e*256 + (((d>>3) ^ (e&7)))*16 + (d&7)*2; }
__device__ __forceinline__ int vt_off(int d, int e){ return d*512 + (((e>>3) ^ (d&7)))*16 + (e&7)*2; }
__device__ __forceinline__ int p_off2(int c, int el){ return c*128 + (((el>>3) ^ (c&7)))*16 + (el&7)*2; }
__device__ __forceinline__ int qt_off(int row, int d){ return row*256 + (((d>>3) ^ (row&7))*16) + (d&7)*2; }

// ------------------------------------------------------------------
// Fused dtype-detect + convert + weight repack (r10 verbatim).
__global__ __launch_bounds__(256) void k_convert_all(
    const void* __restrict__ xsrc, const void* __restrict__ s1, const void* __restrict__ s2,
    const void* __restrict__ s3, const void* __restrict__ s4, const void* __restrict__ s5,
    u16* __restrict__ xb, u16* __restrict__ wpk, u16* __restrict__ wppk,
    u16* __restrict__ bpb, unsigned* __restrict__ flagOut){
  __shared__ unsigned sflag;
  const int tid = threadIdx.x;
  const u16* xs = (const u16*)xsrc;
  if (tid < 64){
    int cnt = 0;
    for (int i = tid; i < 1024; i += 64){
      unsigned e = (xs[2*i] >> 7) & 0xffu;
      cnt += (e >= 143u) ? 1 : 0;
    }
    #pragma unroll
    for (int m = 1; m < 64; m <<= 1) cnt += __shfl_xor(cnt, m);
    if (tid == 0) sflag = (cnt > 16) ? 1u : 0u;
  }
  __syncthreads();
  const unsigned flag = sflag;
  if (blockIdx.x == 0 && tid == 0) *flagOut = flag;
  if (blockIdx.x < 2560 && flag == 0u) return;     // x stays in d_in[0]

  #pragma unroll
  for (int it = 0; it < 4; ++it){
    size_t i = (size_t)blockIdx.x*1024 + it*256 + tid;
    if (i >= 3031200) break;
    const void* src; size_t off; u16* dp;
    if (i < 2621440){ src = xsrc; off = i; dp = xb + i*4; }
    else {
      size_t j = i - 2621440;
      if (j < 409600){
        int iswp = (j >= 307200);
        int j2 = iswp ? (int)(j - 307200) : (int)j;
        int P = j2 * 4;
        int eo = P & 7;
        int grp = P >> 3;
        int lo = grp & 15, g = (grp >> 4) & 3;
        int t2 = grp >> 6;
        int kb = t2 % 20, nt = t2 / 20;
        int n = nt*16 + lo;
        int k = kb*32 + g*8 + eo;
        if (iswp){
          src = s4; off = (size_t)n*160 + (k >> 2); dp = wppk + (size_t)j2*4;
        } else {
          int seg = n / 640, r = n % 640;
          src = (seg==0) ? s1 : (seg==1) ? s2 : s3;
          off = (size_t)r*160 + (k >> 2); dp = wpk + (size_t)j2*4;
        }
      } else { off = j - 409600; src = s5; dp = bpb + off*4; }
    }
    if (flag){
      float4 v = ((const float4*)src)[off];
      ushort4 o;
      o.x = f2bf(v.x); o.y = f2bf(v.y); o.z = f2bf(v.z); o.w = f2bf(v.w);
      *(ushort4*)dp = o;
    } else {
      *(ushort4*)dp = ((const ushort4*)src)[off];
    }
  }
}

// ------------------------------------------------------------------
// FUSED qkv + attention, v2.  One block per (bs,h), 512 thr / 8 waves.
// x staged COALESCED via r10's verified global_load_lds path (BK=64,
// [256 r][64 k] = 32 KB buffers, double-buffered inside k_lds, which is
// free until its epilogue).  A-frags via r10's exact read pattern.
// B-frags register-direct from packed W (r10).  Q -> q-temp in vt_lds ->
// qf regs (r11).  KV phase re-stages x (L2-warm), k->k_lds, vT->vt_lds
// (r11 epilogues).  Attn body r10-verbatim.  Output -> QB.
__global__ __launch_bounds__(512, 2) void attn_fused(
    const u16* __restrict__ xraw, const u16* __restrict__ xb,
    const unsigned* __restrict__ flag, const u16* __restrict__ wpk,
    u16* __restrict__ ob){
  __shared__ char smem[147456];
  char* k_lds  = smem;               // 64 KiB: x-stage dbuf, then k (k_off)
  char* vt_lds = smem + 65536;       // 64 KiB: q-temp (qt), then vT (vt_off)
  char* p_lds  = smem + 131072;      // 16 KiB = 8 waves x [16][64]
  const int tid = threadIdx.x;
  const int lane = tid & 63, wid = tid >> 6;
  const int g = lane >> 4, lo = lane & 15;
  const int n = blockIdx.x;                       // XCD-bijective: 8 x 40
  const int bsh = (n & 7) * 40 + (n >> 3);
  const int bs = bsh / 5, h = bsh % 5;
  const u16* xbase = ((*flag != 0u) ? xb : xraw) + (size_t)bs*256*640;
  const int rg = wid >> 1, cg = wid & 1;          // 4 rowgroups x 2 colgroups
  const f32x4 vzero = {0.f, 0.f, 0.f, 0.f};

  // x staging (r10 A-path verbatim, scaled to 256 rows = 32 chunks):
  // lane -> row l>>3 of chunk, slot l&7, pre-swizzled true chunk (l&7)^srow.
  const int srow = lane >> 3;
  const size_t soff = (size_t)srow*640 + (size_t)(((lane & 7) ^ srow) * 8);

  #define STAGEX(b, kt) do { _Pragma("unroll")                                \
    for (int cc = 0; cc < 4; ++cc){                                           \
      int c_ = wid*4 + cc;                                                    \
      gload16(xbase + (size_t)(kt)*64 + (size_t)c_*8*640 + soff,              \
              k_lds + (b)*32768 + c_*1024);                                   \
    } } while(0)

  #define LOADAF(b) do { _Pragma("unroll")                                    \
    for (int mt = 0; mt < 4; ++mt) _Pragma("unroll")                          \
      for (int ks = 0; ks < 2; ++ks)                                          \
        af[mt][ks] = *(const bf16x8*)(k_lds + (b)*32768 +                     \
                 (rg*64 + mt*16 + lo)*128 + (((ks*4+g) ^ (lo&7))*16));        \
  } while(0)

  // ---------------- Q phase ----------------
  {
    f32x4 qa[4][4];
    #pragma unroll
    for (int mt = 0; mt < 4; ++mt)
      #pragma unroll
      for (int nt = 0; nt < 4; ++nt) qa[mt][nt] = vzero;
    bf16x8 af[4][2], bq[4][2];
    #define LOADBQ(kt) do { _Pragma("unroll")                                 \
      for (int nt = 0; nt < 4; ++nt) _Pragma("unroll")                        \
        for (int ks = 0; ks < 2; ++ks)                                        \
          bq[nt][ks] = *(const bf16x8*)(wpk +                                 \
            (((size_t)(h*8 + cg*4 + nt)*20 + (kt)*2 + ks) << 9) + lane*8);    \
    } while(0)
    #define COMPQ(b) do { LOADAF(b); _Pragma("unroll")                        \
      for (int ks = 0; ks < 2; ++ks) _Pragma("unroll")                        \
        for (int mt = 0; mt < 4; ++mt) _Pragma("unroll")                      \
          for (int nt = 0; nt < 4; ++nt)                                      \
            qa[mt][nt] = __builtin_amdgcn_mfma_f32_16x16x32_bf16(             \
                af[mt][ks], bq[nt][ks], qa[mt][nt], 0, 0, 0);                 \
    } while(0)
    STAGEX(0, 0);
    __syncthreads();
    #pragma unroll 1
    for (int kt2 = 0; kt2 < 5; ++kt2){
      LOADBQ(2*kt2);
      STAGEX(1, 2*kt2 + 1);
      COMPQ(0);
      __syncthreads();
      LOADBQ(2*kt2 + 1);
      if (kt2 < 4) STAGEX(0, 2*kt2 + 2);
      COMPQ(1);
      __syncthreads();
    }
    #undef LOADBQ
    #undef COMPQ
    // q -> q-temp in vt_lds (r11 verbatim)
    #pragma unroll
    for (int mt = 0; mt < 4; ++mt)
      #pragma unroll
      for (int nt = 0; nt < 4; ++nt)
        #pragma unroll
        for (int r = 0; r < 4; ++r){
          int row = rg*64 + mt*16 + g*4 + r;
          int d   = cg*64 + nt*16 + lo;
          *(u16*)(vt_lds + qt_off(row, d)) = f2bf(qa[mt][nt][r]);
        }
  }
  __syncthreads();
  bf16x8 qf[2][4];                                 // this wave's 32 q-rows
  #pragma unroll
  for (int mt2 = 0; mt2 < 2; ++mt2)
    #pragma unroll
    for (int kc = 0; kc < 4; ++kc){
      int row = wid*32 + mt2*16 + lo;
      qf[mt2][kc] = *(const bf16x8*)(vt_lds + row*256 + (((kc*4 + g) ^ (row & 7)) * 16));
    }
  __syncthreads();   // qf drained -> vt_lds free for v

  // ---------------- KV phase ----------------
  {
    f32x4 ak[4][4], av[4][4];
    #pragma unroll
    for (int mt = 0; mt < 4; ++mt)
      #pragma unroll
      for (int nt = 0; nt < 4; ++nt){ ak[mt][nt] = vzero; av[mt][nt] = vzero; }
    bf16x8 af[4][2];
    #define KVSTEP(b, kt) do {                                                \
      LOADAF(b);                                                              \
      { bf16x8 bk[4][2]; _Pragma("unroll")                                    \
        for (int nt = 0; nt < 4; ++nt) _Pragma("unroll")                      \
          for (int ks = 0; ks < 2; ++ks)                                      \
            bk[nt][ks] = *(const bf16x8*)(wpk +                               \
              (((size_t)(40 + h*8 + cg*4 + nt)*20 + (kt)*2 + ks) << 9) + lane*8); \
        _Pragma("unroll")                                                     \
        for (int ks = 0; ks < 2; ++ks) _Pragma("unroll")                      \
          for (int mt = 0; mt < 4; ++mt) _Pragma("unroll")                    \
            for (int nt = 0; nt < 4; ++nt)                                    \
              ak[mt][nt] = __builtin_amdgcn_mfma_f32_16x16x32_bf16(           \
                  af[mt][ks], bk[nt][ks], ak[mt][nt], 0, 0, 0); }             \
      { bf16x8 bv[4][2]; _Pragma("unroll")                                    \
        for (int nt = 0; nt < 4; ++nt) _Pragma("unroll")                      \
          for (int ks = 0; ks < 2; ++ks)                                      \
            bv[nt][ks] = *(const bf16x8*)(wpk +                               \
              (((size_t)(80 + h*8 + cg*4 + nt)*20 + (kt)*2 + ks) << 9) + lane*8); \
        _Pragma("unroll")                                                     \
        for (int ks = 0; ks < 2; ++ks) _Pragma("unroll")                      \
          for (int mt = 0; mt < 4; ++mt) _Pragma("unroll")                    \
            for (int nt = 0; nt < 4; ++nt)                                    \
              av[mt][nt] = __builtin_amdgcn_mfma_f32_16x16x32_bf16(           \
                  af[mt][ks], bv[nt][ks], av[mt][nt], 0, 0, 0); }             \
    } while(0)
    STAGEX(0, 0);
    __syncthreads();
    #pragma unroll 1
    for (int kt2 = 0; kt2 < 5; ++kt2){
      STAGEX(1, 2*kt2 + 1);
      KVSTEP(0, 2*kt2);
      __syncthreads();
      if (kt2 < 4) STAGEX(0, 2*kt2 + 2);
      KVSTEP(1, 2*kt2 + 1);
      __syncthreads();
    }
    #undef KVSTEP
    // k -> k_lds, vT -> vt_lds (r11 verbatim)
    #pragma unroll
    for (int mt = 0; mt < 4; ++mt)
      #pragma unroll
      for (int nt = 0; nt < 4; ++nt)
        #pragma unroll
        for (int r = 0; r < 4; ++r){
          int e = rg*64 + mt*16 + g*4 + r;
          int d = cg*64 + nt*16 + lo;
          *(u16*)(k_lds  + k_off(e, d))  = f2bf(ak[mt][nt][r]);
          *(u16*)(vt_lds + vt_off(d, e)) = f2bf(av[mt][nt][r]);
        }
  }
  __syncthreads();
  #undef STAGEX
  #undef LOADAF

  // ---------------- ATTN (r10-verified body) ----------------
  char* pw = p_lds + wid*2048;
  const float scale = 0.08838834764831845f;
  for (int mt = 0; mt < 2; ++mt){
    const int crow = wid*32 + mt*16;
    f32x4 acc[16];
    #pragma unroll
    for (int et = 0; et < 16; ++et) acc[et] = vzero;
    #pragma unroll
    for (int et = 0; et < 16; ++et)
      #pragma unroll
      for (int kc = 0; kc < 4; ++kc){
        bf16x8 bk = *(const bf16x8*)(k_lds + k_off(et*16 + lo, kc*32 + g*8));
        acc[et] = __builtin_amdgcn_mfma_f32_16x16x32_bf16(qf[mt][kc], bk, acc[et], 0, 0, 0);
      }

    float mx[4] = {-3.0e38f, -3.0e38f, -3.0e38f, -3.0e38f};
    #pragma unroll
    for (int et = 0; et < 16; ++et)
      #pragma unroll
      for (int r = 0; r < 4; ++r){
        float t = acc[et][r] * scale;
        acc[et][r] = t;
        mx[r] = fmaxf(mx[r], t);
      }
    #pragma unroll
    for (int msk = 1; msk < 16; msk <<= 1)
      #pragma unroll
      for (int r = 0; r < 4; ++r) mx[r] = fmaxf(mx[r], __shfl_xor(mx[r], msk));
    float sm[4] = {0.f, 0.f, 0.f, 0.f};
    #pragma unroll
    for (int et = 0; et < 16; ++et)
      #pragma unroll
      for (int r = 0; r < 4; ++r){
        float ex = __expf(acc[et][r] - mx[r]);
        acc[et][r] = ex;
        sm[r] += ex;
      }
    #pragma unroll
    for (int msk = 1; msk < 16; msk <<= 1)
      #pragma unroll
      for (int r = 0; r < 4; ++r) sm[r] += __shfl_xor(sm[r], msk);
    float inv[4];
    #pragma unroll
    for (int r = 0; r < 4; ++r) inv[r] = 1.0f / sm[r];

    f32x4 oacc[8];
    #pragma unroll
    for (int dt = 0; dt < 8; ++dt) oacc[dt] = vzero;

    #pragma unroll
    for (int half = 0; half < 2; ++half)
      #pragma unroll
      for (int sub = 0; sub < 2; ++sub){
        #pragma unroll
        for (int et2 = 0; et2 < 4; ++et2){
          int et = half*8 + sub*4 + et2;
          #pragma unroll
          for (int r = 0; r < 4; ++r)
            *(u16*)(pw + p_off2(g*4 + r, et2*16 + lo)) = f2bf(acc[et][r] * inv[r]);
        }
        asm volatile("s_waitcnt lgkmcnt(0)" ::: "memory");
        bf16x8 pf[2];
        #pragma unroll
        for (int kc = 0; kc < 2; ++kc) pf[kc] = *(const bf16x8*)(pw + p_off2(lo, kc*32 + g*8));
        #pragma unroll
        for (int dt = 0; dt < 8; ++dt)
          #pragma unroll
          for (int kc = 0; kc < 2; ++kc){
            bf16x8 bv = *(const bf16x8*)(vt_lds + vt_off(dt*16 + lo, half*128 + sub*64 + kc*32 + g*8));
            oacc[dt] = __builtin_amdgcn_mfma_f32_16x16x32_bf16(pf[kc], bv, oacc[dt], 0, 0, 0);
          }
        asm volatile("s_waitcnt lgkmcnt(0)" ::: "memory");
      }

    u16* orow = ob + ((size_t)bs*256 + crow)*640 + (size_t)h*128;
    #pragma unroll
    for (int dt = 0; dt < 8; ++dt)
      #pragma unroll
      for (int r = 0; r < 4; ++r)
        orow[(size_t)(g*4 + r)*640 + dt*16 + lo] = f2bf(oacc[dt][r]);
  }
}

// ------------------------------------------------------------------
// Output projection (r10 verbatim): 128x128 tile, BK=64 dbuf A-LDS +
// register-direct packed B, 3 blocks/CU.
__global__ __launch_bounds__(256, 3) void gemm_out(
    const u16* __restrict__ at, const u16* __restrict__ bpk,
    const u16* __restrict__ bpw, void* __restrict__ outp,
    const unsigned* __restrict__ flag){
  __shared__ char lds[32768];
  const int tid = threadIdx.x;
  const int lane = tid & 63, wid = tid >> 6;
  const int g = lane >> 4, lo = lane & 15;
  const int wm = wid >> 1, wn = wid & 1;
  const int m0 = blockIdx.x * 128;
  const int byn8 = blockIdx.y * 8;
  const u16* Ax = at + (size_t)m0*640;

  const int srow = lane >> 3;
  const size_t soff = (size_t)srow*640 + (size_t)(((lane & 7) ^ srow) * 8);

  #define STAGE(b, kt) do { _Pragma("unroll")                                 \
    for (int cc = 0; cc < 4; ++cc){                                           \
      int c_ = wid*4 + cc;                                                    \
      gload16(Ax + (size_t)(kt)*64 + (size_t)c_*8*640 + soff,                 \
              lds + (b)*16384 + c_*1024);                                     \
    } } while(0)

  bf16x8 bfr[4][2];
  #define LOADB(kt) do { _Pragma("unroll")                                    \
    for (int nt = 0; nt < 4; ++nt) _Pragma("unroll")                          \
      for (int ks = 0; ks < 2; ++ks)                                          \
        bfr[nt][ks] = *(const bf16x8*)(bpk +                                  \
          (((size_t)(byn8 + wn*4 + nt)*20 + (kt)*2 + ks) << 9) + lane*8);     \
  } while(0)

  f32x4 acc[4][4];
  const f32x4 vzero = {0.f, 0.f, 0.f, 0.f};
  #pragma unroll
  for (int mt = 0; mt < 4; ++mt)
    #pragma unroll
    for (int nt = 0; nt < 4; ++nt) acc[mt][nt] = vzero;

  #define COMPUTE(b) do { _Pragma("unroll")                                   \
    for (int ks = 0; ks < 2; ++ks){                                           \
      bf16x8 af[4];                                                           \
      _Pragma("unroll")                                                       \
      for (int mt = 0; mt < 4; ++mt)                                          \
        af[mt] = *(const bf16x8*)(lds + (b)*16384 +                           \
                   (wm*64 + mt*16 + lo)*128 + (((ks*4+g) ^ (lo&7))*16));      \
      _Pragma("unroll")                                                       \
      for (int mt = 0; mt < 4; ++mt) _Pragma("unroll")                        \
        for (int nt = 0; nt < 4; ++nt)                                        \
          acc[mt][nt] = __builtin_amdgcn_mfma_f32_16x16x32_bf16(              \
              af[mt], bfr[nt][ks], acc[mt][nt], 0, 0, 0);                     \
    } } while(0)

  STAGE(0, 0);
  __syncthreads();
  #pragma unroll 1
  for (int kt2 = 0; kt2 < 5; ++kt2){
    LOADB(2*kt2);
    STAGE(1, 2*kt2 + 1);
    COMPUTE(0);
    __syncthreads();
    LOADB(2*kt2 + 1);
    if (kt2 < 4) STAGE(0, 2*kt2 + 2);
    COMPUTE(1);
    __syncthreads();
  }
  #undef STAGE
  #undef LOADB
  #undef COMPUTE

  const bool f32out = (*flag != 0u);
  #pragma unroll
  for (int mt = 0; mt < 4; ++mt)
    #pragma unroll
    for (int nt = 0; nt < 4; ++nt)
      #pragma unroll
      for (int r = 0; r < 4; ++r){
        int m  = m0 + wm*64 + mt*16 + g*4 + r;
        int nn = wn*64 + nt*16 + lo;
        int col = blockIdx.y*128 + nn;
        float v = acc[mt][nt][r] + bf2f(bpw[col]);
        if (f32out) ((float*)outp)[(size_t)m*640 + col] = v;
        else        ((u16*)outp)[(size_t)m*640 + col]   = f2bf(v);
      }
}

// ------------------------------------------------------------------
extern "C" void kernel_launch(void* const* d_in, const int* in_sizes, int n_in,
                              void* d_out, int out_size, void* d_ws, size_t ws_size,
                              hipStream_t stream) {
  (void)in_sizes; (void)n_in; (void)out_size; (void)ws_size;
  char* ws = (char*)d_ws;
  const size_t SZ = (size_t)16384 * 640 * 2;     // 20,971,520 B
  u16* XB   = (u16*)(ws);
  u16* QB   = (u16*)(ws + SZ);                    // attn output
  u16* WPK  = (u16*)(ws + 4*SZ);                  // packed qkv W: 1,228,800 u16
  u16* WPPK = WPK + 1228800;                      // packed Wp:     409,600 u16
  u16* BPB  = WPPK + 409600;                      // [640]
  unsigned* FLAG = (unsigned*)(BPB + 640);

  k_convert_all<<<2961, 256, 0, stream>>>(d_in[0], d_in[1], d_in[2], d_in[3],
                                          d_in[4], d_in[5], XB, WPK, WPPK, BPB, FLAG);

  attn_fused<<<320, 512, 0, stream>>>((const u16*)d_in[0], XB, FLAG, WPK, QB);

  gemm_out<<<dim3(128, 5), 256, 0, stream>>>(QB, WPPK, BPB, d_out, FLAG);
}

// Round 14
// 160.376 us; speedup vs baseline: 1.1779x; 1.1779x over previous
//
#include <hip/hip_runtime.h>

// B=2, S=32, C=256, L=640, H=5, D=128.  M = B*S*C = 16384, L = 640 = H*D.
//
// ws layout (bytes):
//   XPK  @ 0    : x repacked in MFMA A-frag order [1024 mt][20 kb][64 lane][8]
//                 (written ALWAYS by convert; reused as attn_out AT after qkv)
//   QB   @ SZ   : q bf16 [16384][640];  KB @ 2SZ;  VTB @ 3SZ (v transposed)
//   WPK  @ 4SZ  : Wq|Wk|Wv packed frag-order [120 nt][20 kb][64][8]
//   WPPK        : Wp packed frag-order [40 nt][20 kb][64][8]
//   BPB  bp bf16 [640];  FLAG u32 (1 = inputs fp32)

typedef unsigned short u16;
typedef __bf16 bf16x8 __attribute__((ext_vector_type(8)));
typedef float f32x4 __attribute__((ext_vector_type(4)));

__device__ __forceinline__ u16 f2bf(float f){
  union { float f; unsigned u; } v; v.f = f;
  unsigned r = v.u + 0x7fffu + ((v.u >> 16) & 1u);
  return (u16)(r >> 16);
}
__device__ __forceinline__ float bf2f(u16 u){
  union { unsigned u; float f; } v; v.u = ((unsigned)u) << 16;
  return v.f;
}

__device__ __forceinline__ void gload16(const u16* g, char* l){
  __builtin_amdgcn_global_load_lds((const __attribute__((address_space(1))) void*)g,
                                   (__attribute__((address_space(3))) void*)l, 16, 0, 0);
}

// ---- attention LDS swizzles (verified r1-r10) ----
__device__ __forceinline__ int k_off (int e, int d){ return e*256 + (((d>>3) ^ (e&7)))*16 + (d&7)*2; }
__device__ __forceinline__ int vt_off(int d, int e){ return d*512 + (((e>>3) ^ (d&7)))*16 + (e&7)*2; }
__device__ __forceinline__ int p_off2(int c, int el){ return c*128 + (((el>>3) ^ (c&7)))*16 + (el&7)*2; }

// ------------------------------------------------------------------
// Fused dtype-detect + convert + repack of BOTH operands into MFMA
// fragment order.  x -> XPK [mt][kb][lane][8]: lane l of tile (mt,kb) holds
// x[mt*16 + (l&15)][kb*32 + (l>>4)*8 + e].  Weights -> WPK/WPPK (r10).
// word4 segments: x 2621440 | wqkv 307200 | wp 102400 | bp 40.
__global__ __launch_bounds__(256) void k_convert_all(
    const void* __restrict__ xsrc, const void* __restrict__ s1, const void* __restrict__ s2,
    const void* __restrict__ s3, const void* __restrict__ s4, const void* __restrict__ s5,
    u16* __restrict__ xpk, u16* __restrict__ wpk, u16* __restrict__ wppk,
    u16* __restrict__ bpb, unsigned* __restrict__ flagOut){
  __shared__ unsigned sflag;
  const int tid = threadIdx.x;
  const u16* xs = (const u16*)xsrc;
  if (tid < 64){
    int cnt = 0;
    for (int i = tid; i < 1024; i += 64){
      unsigned e = (xs[2*i] >> 7) & 0xffu;
      cnt += (e >= 143u) ? 1 : 0;
    }
    #pragma unroll
    for (int m = 1; m < 64; m <<= 1) cnt += __shfl_xor(cnt, m);
    if (tid == 0) sflag = (cnt > 16) ? 1u : 0u;
  }
  __syncthreads();
  const unsigned flag = sflag;
  if (blockIdx.x == 0 && tid == 0) *flagOut = flag;

  #pragma unroll
  for (int it = 0; it < 4; ++it){
    size_t i = (size_t)blockIdx.x*1024 + it*256 + tid;
    if (i >= 3031200) break;
    const void* src; size_t off; u16* dp;
    if (i < 2621440){
      // x repack: word4 i -> u16 P=i*4; e0=(i&1)*4; grp=i>>1; lane=grp&63;
      // t=grp>>6; kb=t%20; mt=t/20.
      int e0 = ((int)i & 1) * 4;
      int grp = (int)(i >> 1);
      int lane = grp & 63;
      int t = grp >> 6;
      int kb = t % 20, mt = t / 20;
      int row = mt*16 + (lane & 15);
      int col = kb*32 + ((lane >> 4) & 3)*8 + e0;
      src = xsrc; off = ((size_t)row*640 + col) >> 2; dp = xpk + i*4;
    } else {
      size_t j = i - 2621440;
      if (j < 409600){
        int iswp = (j >= 307200);
        int j2 = iswp ? (int)(j - 307200) : (int)j;
        int P = j2 * 4;
        int eo = P & 7;
        int grp = P >> 3;
        int lo = grp & 15, g = (grp >> 4) & 3;
        int t2 = grp >> 6;
        int kb = t2 % 20, nt = t2 / 20;
        int n = nt*16 + lo;
        int k = kb*32 + g*8 + eo;
        if (iswp){
          src = s4; off = (size_t)n*160 + (k >> 2); dp = wppk + (size_t)j2*4;
        } else {
          int seg = n / 640, r = n % 640;
          src = (seg==0) ? s1 : (seg==1) ? s2 : s3;
          off = (size_t)r*160 + (k >> 2); dp = wpk + (size_t)j2*4;
        }
      } else { off = j - 409600; src = s5; dp = bpb + off*4; }
    }
    if (flag){
      float4 v = ((const float4*)src)[off];
      ushort4 o;
      o.x = f2bf(v.x); o.y = f2bf(v.y); o.z = f2bf(v.z); o.w = f2bf(v.w);
      *(ushort4*)dp = o;
    } else {
      *(ushort4*)dp = ((const ushort4*)src)[off];
    }
  }
}

// ------------------------------------------------------------------
// NO-LDS, NO-BARRIER QKV GEMM.  Both operands packed in frag order: every
// fragment load is one coalesced global_load_dwordx4 at base + lane*16B.
// grid (128 m-blocks, 15 n-groups), 256 thr = 4 waves (2x2, 64x64/wave).
// Per K-step (BK=32): 8 coalesced loads + 16 MFMA; 20 independent steps —
// the compiler software-pipelines freely (no barriers to stop it).
// Epilogue = r10 qkv scatter (q/k rowmajor, v transposed) verbatim.
__global__ __launch_bounds__(256, 4) void gemm_qkv_nl(
    const u16* __restrict__ apk, const u16* __restrict__ bpk,
    u16* __restrict__ qb, u16* __restrict__ kb, u16* __restrict__ vtb){
  const int tid = threadIdx.x;
  const int lane = tid & 63, wid = tid >> 6;
  const int g = lane >> 4, lo = lane & 15;
  const int wm = wid >> 1, wn = wid & 1;
  const int mtb = blockIdx.x*8 + wm*4;             // global 16-row tile base
  const int ntb = blockIdx.y*8 + wn*4;             // global 16-col tile base

  f32x4 acc[4][4];
  const f32x4 vzero = {0.f, 0.f, 0.f, 0.f};
  #pragma unroll
  for (int mt = 0; mt < 4; ++mt)
    #pragma unroll
    for (int nt = 0; nt < 4; ++nt) acc[mt][nt] = vzero;

  const u16* ab = apk + ((size_t)mtb*20 << 9) + lane*8;
  const u16* bb = bpk + ((size_t)ntb*20 << 9) + lane*8;

  #pragma unroll 2
  for (int kb_ = 0; kb_ < 20; ++kb_){
    bf16x8 af[4], bf[4];
    #pragma unroll
    for (int mt = 0; mt < 4; ++mt)
      af[mt] = *(const bf16x8*)(ab + (((size_t)mt*20 + kb_) << 9));
    #pragma unroll
    for (int nt = 0; nt < 4; ++nt)
      bf[nt] = *(const bf16x8*)(bb + (((size_t)nt*20 + kb_) << 9));
    #pragma unroll
    for (int mt = 0; mt < 4; ++mt)
      #pragma unroll
      for (int nt = 0; nt < 4; ++nt)
        acc[mt][nt] = __builtin_amdgcn_mfma_f32_16x16x32_bf16(af[mt], bf[nt], acc[mt][nt], 0, 0, 0);
  }

  // ---- epilogue (r10 verbatim) ----
  const int ny = blockIdx.y;
  const int p = ny / 5, h = ny % 5;
  #pragma unroll
  for (int mt = 0; mt < 4; ++mt)
    #pragma unroll
    for (int nt = 0; nt < 4; ++nt)
      #pragma unroll
      for (int r = 0; r < 4; ++r){
        int m  = blockIdx.x*128 + wm*64 + mt*16 + g*4 + r;
        int nn = wn*64 + nt*16 + lo;
        u16 val = f2bf(acc[mt][nt][r]);
        if (p == 0)      qb[(size_t)m*640 + h*128 + nn] = val;
        else if (p == 1) kb[(size_t)m*640 + h*128 + nn] = val;
        else             vtb[((size_t)(m >> 8)*5 + h)*32768 + (size_t)nn*256 + (m & 255)] = val;
      }
}

// ------------------------------------------------------------------
// Attention (r9/r10, passed): 512 threads / 8 waves, grid = 320.
__global__ __launch_bounds__(512, 1) void attn_fwd(const u16* __restrict__ qb,
    const u16* __restrict__ kb, const u16* __restrict__ vtb, u16* __restrict__ ob){
  __shared__ char smem[147456];
  char* k_lds  = smem;
  char* vt_lds = smem + 65536;
  char* p_lds  = smem + 131072;
  const int tid = threadIdx.x;
  const int bsh = blockIdx.x;
  const int bs = bsh / 5, h = bsh % 5;
  const u16* kbase = kb + (size_t)bs*256*640 + (size_t)h*128;
  const u16* vbase = vtb + (size_t)bsh*32768;
  #pragma unroll 4
  for (int i = 0; i < 8; ++i){
    int idx = i*512 + tid;
    int e = idx >> 4, cd = idx & 15;
    uint4 kv = *(const uint4*)(kbase + (size_t)e*640 + cd*8);
    *(uint4*)(k_lds + e*256 + ((cd ^ (e & 7)))*16) = kv;
    int d = idx >> 5, ce = idx & 31;
    uint4 vv = *(const uint4*)(vbase + d*256 + ce*8);
    *(uint4*)(vt_lds + d*512 + ((ce ^ (d & 7)))*16) = vv;
  }
  __syncthreads();
  const int lane = tid & 63, wid = tid >> 6;
  const int g = lane >> 4, lo = lane & 15;
  char* pw = p_lds + wid*2048;
  const float scale = 0.08838834764831845f;
  const f32x4 vzero = {0.f, 0.f, 0.f, 0.f};

  for (int mt = 0; mt < 2; ++mt){
    const int crow = wid*32 + mt*16;
    const u16* qr = qb + ((size_t)bs*256 + crow + lo)*640 + (size_t)h*128;
    bf16x8 qf[4];
    #pragma unroll
    for (int kc = 0; kc < 4; ++kc) qf[kc] = *(const bf16x8*)(qr + kc*32 + g*8);

    f32x4 acc[16];
    #pragma unroll
    for (int et = 0; et < 16; ++et) acc[et] = vzero;
    #pragma unroll
    for (int et = 0; et < 16; ++et)
      #pragma unroll
      for (int kc = 0; kc < 4; ++kc){
        bf16x8 bk = *(const bf16x8*)(k_lds + k_off(et*16 + lo, kc*32 + g*8));
        acc[et] = __builtin_amdgcn_mfma_f32_16x16x32_bf16(qf[kc], bk, acc[et], 0, 0, 0);
      }

    float mx[4] = {-3.0e38f, -3.0e38f, -3.0e38f, -3.0e38f};
    #pragma unroll
    for (int et = 0; et < 16; ++et)
      #pragma unroll
      for (int r = 0; r < 4; ++r){
        float t = acc[et][r] * scale;
        acc[et][r] = t;
        mx[r] = fmaxf(mx[r], t);
      }
    #pragma unroll
    for (int msk = 1; msk < 16; msk <<= 1)
      #pragma unroll
      for (int r = 0; r < 4; ++r) mx[r] = fmaxf(mx[r], __shfl_xor(mx[r], msk));
    float sm[4] = {0.f, 0.f, 0.f, 0.f};
    #pragma unroll
    for (int et = 0; et < 16; ++et)
      #pragma unroll
      for (int r = 0; r < 4; ++r){
        float ex = __expf(acc[et][r] - mx[r]);
        acc[et][r] = ex;
        sm[r] += ex;
      }
    #pragma unroll
    for (int msk = 1; msk < 16; msk <<= 1)
      #pragma unroll
      for (int r = 0; r < 4; ++r) sm[r] += __shfl_xor(sm[r], msk);
    float inv[4];
    #pragma unroll
    for (int r = 0; r < 4; ++r) inv[r] = 1.0f / sm[r];

    f32x4 oacc[8];
    #pragma unroll
    for (int dt = 0; dt < 8; ++dt) oacc[dt] = vzero;

    #pragma unroll
    for (int half = 0; half < 2; ++half)
      #pragma unroll
      for (int sub = 0; sub < 2; ++sub){
        #pragma unroll
        for (int et2 = 0; et2 < 4; ++et2){
          int et = half*8 + sub*4 + et2;
          #pragma unroll
          for (int r = 0; r < 4; ++r)
            *(u16*)(pw + p_off2(g*4 + r, et2*16 + lo)) = f2bf(acc[et][r] * inv[r]);
        }
        asm volatile("s_waitcnt lgkmcnt(0)" ::: "memory");
        bf16x8 pf[2];
        #pragma unroll
        for (int kc = 0; kc < 2; ++kc) pf[kc] = *(const bf16x8*)(pw + p_off2(lo, kc*32 + g*8));
        #pragma unroll
        for (int dt = 0; dt < 8; ++dt)
          #pragma unroll
          for (int kc = 0; kc < 2; ++kc){
            bf16x8 bv = *(const bf16x8*)(vt_lds + vt_off(dt*16 + lo, half*128 + sub*64 + kc*32 + g*8));
            oacc[dt] = __builtin_amdgcn_mfma_f32_16x16x32_bf16(pf[kc], bv, oacc[dt], 0, 0, 0);
          }
        asm volatile("s_waitcnt lgkmcnt(0)" ::: "memory");
      }

    u16* orow = ob + ((size_t)bs*256 + crow)*640 + (size_t)h*128;
    #pragma unroll
    for (int dt = 0; dt < 8; ++dt)
      #pragma unroll
      for (int r = 0; r < 4; ++r)
        orow[(size_t)(g*4 + r)*640 + dt*16 + lo] = f2bf(oacc[dt][r]);
  }
}

// ------------------------------------------------------------------
// Output projection (r10 verbatim): 128x128 tile, BK=64 dbuf A-LDS +
// register-direct packed B, 3 blocks/CU.
__global__ __launch_bounds__(256, 3) void gemm_out(
    const u16* __restrict__ at, const u16* __restrict__ bpk,
    const u16* __restrict__ bpw, void* __restrict__ outp,
    const unsigned* __restrict__ flag){
  __shared__ char lds[32768];
  const int tid = threadIdx.x;
  const int lane = tid & 63, wid = tid >> 6;
  const int g = lane >> 4, lo = lane & 15;
  const int wm = wid >> 1, wn = wid & 1;
  const int m0 = blockIdx.x * 128;
  const int byn8 = blockIdx.y * 8;
  const u16* Ax = at + (size_t)m0*640;

  const int srow = lane >> 3;
  const size_t soff = (size_t)srow*640 + (size_t)(((lane & 7) ^ srow) * 8);

  #define STAGE(b, kt) do { _Pragma("unroll")                                 \
    for (int cc = 0; cc < 4; ++cc){                                           \
      int c_ = wid*4 + cc;                                                    \
      gload16(Ax + (size_t)(kt)*64 + (size_t)c_*8*640 + soff,                 \
              lds + (b)*16384 + c_*1024);                                     \
    } } while(0)

  bf16x8 bfr[4][2];
  #define LOADB(kt) do { _Pragma("unroll")                                    \
    for (int nt = 0; nt < 4; ++nt) _Pragma("unroll")                          \
      for (int ks = 0; ks < 2; ++ks)                                          \
        bfr[nt][ks] = *(const bf16x8*)(bpk +                                  \
          (((size_t)(byn8 + wn*4 + nt)*20 + (kt)*2 + ks) << 9) + lane*8);     \
  } while(0)

  f32x4 acc[4][4];
  const f32x4 vzero = {0.f, 0.f, 0.f, 0.f};
  #pragma unroll
  for (int mt = 0; mt < 4; ++mt)
    #pragma unroll
    for (int nt = 0; nt < 4; ++nt) acc[mt][nt] = vzero;

  #define COMPUTE(b) do { _Pragma("unroll")                                   \
    for (int ks = 0; ks < 2; ++ks){                                           \
      bf16x8 af[4];                                                           \
      _Pragma("unroll")                                                       \
      for (int mt = 0; mt < 4; ++mt)                                          \
        af[mt] = *(const bf16x8*)(lds + (b)*16384 +                           \
                   (wm*64 + mt*16 + lo)*128 + (((ks*4+g) ^ (lo&7))*16));      \
      _Pragma("unroll")                                                       \
      for (int mt = 0; mt < 4; ++mt) _Pragma("unroll")                        \
        for (int nt = 0; nt < 4; ++nt)                                        \
          acc[mt][nt] = __builtin_amdgcn_mfma_f32_16x16x32_bf16(              \
              af[mt], bfr[nt][ks], acc[mt][nt], 0, 0, 0);                     \
    } } while(0)

  STAGE(0, 0);
  __syncthreads();
  #pragma unroll 1
  for (int kt2 = 0; kt2 < 5; ++kt2){
    LOADB(2*kt2);
    STAGE(1, 2*kt2 + 1);
    COMPUTE(0);
    __syncthreads();
    LOADB(2*kt2 + 1);
    if (kt2 < 4) STAGE(0, 2*kt2 + 2);
    COMPUTE(1);
    __syncthreads();
  }
  #undef STAGE
  #undef LOADB
  #undef COMPUTE

  const bool f32out = (*flag != 0u);
  #pragma unroll
  for (int mt = 0; mt < 4; ++mt)
    #pragma unroll
    for (int nt = 0; nt < 4; ++nt)
      #pragma unroll
      for (int r = 0; r < 4; ++r){
        int m  = m0 + wm*64 + mt*16 + g*4 + r;
        int nn = wn*64 + nt*16 + lo;
        int col = blockIdx.y*128 + nn;
        float v = acc[mt][nt][r] + bf2f(bpw[col]);
        if (f32out) ((float*)outp)[(size_t)m*640 + col] = v;
        else        ((u16*)outp)[(size_t)m*640 + col]   = f2bf(v);
      }
}

// ------------------------------------------------------------------
extern "C" void kernel_launch(void* const* d_in, const int* in_sizes, int n_in,
                              void* d_out, int out_size, void* d_ws, size_t ws_size,
                              hipStream_t stream) {
  (void)in_sizes; (void)n_in; (void)out_size; (void)ws_size;
  char* ws = (char*)d_ws;
  const size_t SZ = (size_t)16384 * 640 * 2;     // 20,971,520 B
  u16* XPK  = (u16*)(ws);                         // packed x (10,485,760 u16)
  u16* QB   = (u16*)(ws + SZ);
  u16* KB   = (u16*)(ws + 2*SZ);
  u16* VTB  = (u16*)(ws + 3*SZ);
  u16* AT   = (u16*)(ws);                         // attn out reuses XPK
  u16* WPK  = (u16*)(ws + 4*SZ);                  // packed qkv W: 1,228,800 u16
  u16* WPPK = WPK + 1228800;                      // packed Wp:     409,600 u16
  u16* BPB  = WPPK + 409600;                      // [640]
  unsigned* FLAG = (unsigned*)(BPB + 640);

  k_convert_all<<<2961, 256, 0, stream>>>(d_in[0], d_in[1], d_in[2], d_in[3],
                                          d_in[4], d_in[5], XPK, WPK, WPPK, BPB, FLAG);

  gemm_qkv_nl<<<dim3(128, 15), 256, 0, stream>>>(XPK, WPK, QB, KB, VTB);

  attn_fwd<<<320, 512, 0, stream>>>(QB, KB, VTB, AT);

  gemm_out<<<dim3(128, 5), 256, 0, stream>>>(AT, WPPK, BPB, d_out, FLAG);
}